// Round 4
// baseline (294.306 us; speedup 1.0000x reference)
//
#include <hip/hip_runtime.h>
#include <cstddef>

#define D_MODEL 1024
#define NH 16
#define HD 64
#define BATCH 4
#define SEQ 2048
#define MTOT (BATCH * SEQ)  // 8192

typedef _Float16 half8 __attribute__((ext_vector_type(8)));
typedef _Float16 half4v __attribute__((ext_vector_type(4)));
typedef float f32x4 __attribute__((ext_vector_type(4)));

#if __has_builtin(__builtin_amdgcn_exp2f)
#define EXP2(x) __builtin_amdgcn_exp2f(x)
#else
#define EXP2(x) __expf((x)*0.69314718056f)
#endif

// async global->LDS, 16B per lane. LDS dest must be wave-uniform base (+lane*16 implicit).
#define ASYNC_COPY16(g, l)                                                    \
    __builtin_amdgcn_global_load_lds(                                         \
        (__attribute__((address_space(1))) const void*)(g),                   \
        (__attribute__((address_space(3))) void*)(l), 16, 0, 0)

// Swizzled LDS fragment read: logical element (R, CH f16-cols) of a [*][64]
// f16 tile lives at byte R*128 + ((CH*2) ^ ((R&7)<<4)).  Staging applies the
// inverse permutation on the GLOBAL source address (linear dest + inverse-swz
// source + swz read), so a wave's 64 lanes reading one column-slice across 16
// rows land on distinct 16B slots -> 2-way (free) instead of 16-way.
#define LDSFRAG(S, R, CH)                                                     \
    (*(const half8*)((const char*)(S) + ((R) << 7) +                          \
                     ((((CH) << 1)) ^ (((R) & 7) << 4))))

// ---------------------------------------------------------------------------
// Fused prep (unchanged):
//   blocks 0..255    : x fp32 -> f16 (4096 half8 chunks per block)
//   blocks 256..1279 : 4 weight matrices fp32 [k][n] -> f16 transposed [n][k]
// ---------------------------------------------------------------------------
__global__ __launch_bounds__(256) void prep(
    const float* __restrict__ x, _Float16* __restrict__ xh,
    const float* __restrict__ W0, const float* __restrict__ W1,
    const float* __restrict__ W2, const float* __restrict__ W3,
    _Float16* __restrict__ T0, _Float16* __restrict__ T1,
    _Float16* __restrict__ T2, _Float16* __restrict__ T3)
{
    __shared__ float T[64][65];
    const int bid = blockIdx.x;
    if (bid < 256) {
        const size_t base = (size_t)bid * 4096 + threadIdx.x;
#pragma unroll
        for (int it = 0; it < 16; ++it) {
            const size_t i = base + (size_t)it * 256;
            const float4* p = (const float4*)x + 2 * i;
            float4 a = p[0], b = p[1];
            half8 h;
            h[0] = (_Float16)a.x; h[1] = (_Float16)a.y; h[2] = (_Float16)a.z; h[3] = (_Float16)a.w;
            h[4] = (_Float16)b.x; h[5] = (_Float16)b.y; h[6] = (_Float16)b.z; h[7] = (_Float16)b.w;
            *((half8*)xh + i) = h;
        }
    } else {
        const int t = bid - 256;
        const int mtx = t >> 8;
        const float* W = (mtx == 0) ? W0 : (mtx == 1) ? W1 : (mtx == 2) ? W2 : W3;
        _Float16*   Wt = (mtx == 0) ? T0 : (mtx == 1) ? T1 : (mtx == 2) ? T2 : T3;
        const int tile = t & 255;
        const int k0 = (tile >> 4) * 64, n0 = (tile & 15) * 64;
        const int r = threadIdx.x >> 4, c4 = (threadIdx.x & 15) * 4;

#pragma unroll
        for (int i = 0; i < 4; ++i) {
            float4 v = *(const float4*)(W + (size_t)(k0 + r + 16 * i) * 1024 + n0 + c4);
            T[r + 16 * i][c4 + 0] = v.x; T[r + 16 * i][c4 + 1] = v.y;
            T[r + 16 * i][c4 + 2] = v.z; T[r + 16 * i][c4 + 3] = v.w;
        }
        __syncthreads();
#pragma unroll
        for (int i = 0; i < 4; ++i) {
            const int n = r + 16 * i;
            half4v h;
            h[0] = (_Float16)T[c4 + 0][n]; h[1] = (_Float16)T[c4 + 1][n];
            h[2] = (_Float16)T[c4 + 2][n]; h[3] = (_Float16)T[c4 + 3][n];
            *(half4v*)(Wt + (size_t)(n0 + n) * 1024 + k0 + c4) = h;
        }
    }
}

// ---------------------------------------------------------------------------
// 256x256-tile 4-phase-per-K-tile MFMA GEMM (T2+T3+T4+T5 stack).
// 512 thr = 8 waves (2M x 4N), per-wave C = 128x64, BK=64, NT=16 K-tiles.
// LDS 128 KiB: As/Bs[2][256][64] double-buffered, XOR-swizzled reads.
// Phases = C-quadrants (mh,nh) in order (0,0),(0,1),(1,1),(1,0), 16 MFMAs
// each, frag-reg reuse. One half-tile staged per phase.
//
// Counted-vmcnt schedule (race-freedom verified in round 3, refcheck'd):
//   invariant entering tile kt: in-flight = {A0(kt+1), B1(kt+1)} (4 loads).
//   P1 stages A1(kt+1); P2 B0(kt+1); P3 A0(kt+2); P4 B1(kt+2) -> 12 in
//   flight; s_waitcnt vmcnt(4) AT P4 (before its barrier) retires the 8
//   oldest = exactly all of tile kt+1, two barriers before tile kt+1's first
//   ds_read.  kt >= NT-2 uses vmcnt(0) (kt+2 stages skipped).  Prologue
//   issues {A1(0),B1(0),A0(0),B0(0),A0(1),B1(1)} then vmcnt(4)+barrier.
//   Write-after-read: every stage dest's last ds_read completed >=1 full
//   barrier before the stage issues.
//
// Round-4 change vs round 3: REMOVED all sched_barrier(0) pins and the
// lgkmcnt(0) drains (m141 lesson: order-pinning defeats the compiler's
// near-optimal fine-grained lgkm scheduling; all LDS reads here are
// compiler-visible so MFMA data deps are already enforced).  Barrier/wait
// SEQUENCE is unchanged from the passing round-3 kernel.
// QKV=1: 384 blocks = 32 M x 12 N (N fused Q|K|V); z=nb>>2 selects matrix.
//        z in {0,1}: f16 [bh][s][hd]; z==2: V transposed [bh][d][s].
// QKV=0: 128 blocks = 32 M x 4 N, f32 [m][n] output.
// ---------------------------------------------------------------------------
template <int QKV>
__global__ __launch_bounds__(512, 2) void gemm_mfma(
    const _Float16* __restrict__ A,
    const _Float16* __restrict__ Bt0, const _Float16* __restrict__ Bt1, const _Float16* __restrict__ Bt2,
    const float* __restrict__ bi0, const float* __restrict__ bi1, const float* __restrict__ bi2,
    void* __restrict__ C0, void* __restrict__ C1, void* __restrict__ C2)
{
    constexpr int NT = 16;  // K=1024 / BK=64
    __shared__ _Float16 As[2][256][64];
    __shared__ _Float16 Bs[2][256][64];

    const int L = blockIdx.x;
    int y, z, xb;
    if (QKV) {  // 384 blocks, bijective XCD swizzle (384%8==0)
        const int wg = (L & 7) * 48 + (L >> 3);
        y = wg / 12;
        const int cn = wg % 12;
        z = cn >> 2; xb = cn & 3;
    } else {    // 128 blocks
        const int wg = (L & 7) * 16 + (L >> 3);
        y = wg >> 2; z = 0; xb = wg & 3;
    }

    const _Float16* Bt = (z == 0) ? Bt0 : (z == 1) ? Bt1 : Bt2;
    const float*   bia = (z == 0) ? bi0 : (z == 1) ? bi1 : bi2;
    void*            C = (z == 0) ? C0  : (z == 1) ? C1  : C2;

    const int tid  = threadIdx.x;
    const int w    = tid >> 6;           // 0..7
    const int lane = tid & 63;
    const int l15  = lane & 15;
    const int lg   = lane >> 4;
    const int m0 = y * 256;
    const int n0 = xb * 256;
    const int wm = (w >> 2) * 128;       // 2 M-halves
    const int wn = (w & 3) * 64;         // 4 N-quarters

    // per-lane global source (inverse-swizzled column within the 64-wide K-slab)
    const int rsub = lane >> 3;                  // 0..7 (row within 8-row chunk)
    const int csw  = ((lane & 7) ^ rsub) * 8;    // f16 cols
    const _Float16* gA = A  + (size_t)(m0 + rsub) * 1024 + csw;
    const _Float16* gB = Bt + (size_t)(n0 + rsub) * 1024 + csw;

    // Stage one half-tile (16 KB = 8 waves x 2 issues x 1 KB, linear LDS rows).
    // A-mh rows: {0-63,128-191} + mh*64 ; B-nh rows: stripes s*64 + nh*32 + [0,32)
#define STAGE_A(kt_, mh_) do { const int _t = (kt_); if (_t < NT) {           \
        const size_t _k0 = (size_t)_t * 64;                                   \
        _Pragma("unroll") for (int _i = 0; _i < 2; ++_i) {                    \
            const int _c = 2 * w + _i;                                        \
            const int _r = _c * 8 + ((_c & 8) ? 64 : 0) + (mh_) * 64;         \
            ASYNC_COPY16(gA + (size_t)_r * 1024 + _k0, &As[_t & 1][_r][0]);   \
        } } } while (0)
#define STAGE_B(kt_, nh_) do { const int _t = (kt_); if (_t < NT) {           \
        const size_t _k0 = (size_t)_t * 64;                                   \
        _Pragma("unroll") for (int _i = 0; _i < 2; ++_i) {                    \
            const int _c = 2 * w + _i;                                        \
            const int _r = (_c >> 2) * 64 + (nh_) * 32 + (_c & 3) * 8;        \
            ASYNC_COPY16(gB + (size_t)_r * 1024 + _k0, &Bs[_t & 1][_r][0]);   \
        } } } while (0)
#define READ_A(mh_) do {                                                      \
        _Pragma("unroll") for (int _q = 0; _q < 4; ++_q)                      \
        _Pragma("unroll") for (int _kk = 0; _kk < 2; ++_kk)                   \
            af[_q][_kk] = LDSFRAG(&As[cur][0][0],                             \
                wm + 16 * (4 * (mh_) + _q) + l15, 32 * _kk + 8 * lg);         \
    } while (0)
#define READ_B(nh_) do {                                                      \
        _Pragma("unroll") for (int _p = 0; _p < 2; ++_p)                      \
        _Pragma("unroll") for (int _kk = 0; _kk < 2; ++_kk)                   \
            bf[_p][_kk] = LDSFRAG(&Bs[cur][0][0],                             \
                wn + 16 * (2 * (nh_) + _p) + l15, 32 * _kk + 8 * lg);         \
    } while (0)
#define DO_MFMA(mh_, nh_) do {                                                \
        __builtin_amdgcn_s_setprio(1);                                        \
        _Pragma("unroll") for (int _q = 0; _q < 4; ++_q)                      \
        _Pragma("unroll") for (int _p = 0; _p < 2; ++_p)                      \
        _Pragma("unroll") for (int _kk = 0; _kk < 2; ++_kk)                   \
            acc[4 * (mh_) + _q][2 * (nh_) + _p] =                             \
                __builtin_amdgcn_mfma_f32_16x16x32_f16(                       \
                    af[_q][_kk], bf[_p][_kk],                                 \
                    acc[4 * (mh_) + _q][2 * (nh_) + _p], 0, 0, 0);            \
        __builtin_amdgcn_s_setprio(0);                                        \
    } while (0)
#define BAR() __builtin_amdgcn_s_barrier()
#define WAITVM(n_) asm volatile("s_waitcnt vmcnt(" #n_ ")" ::: "memory")

    // prologue: order matters for the counted-retirement invariant
    STAGE_A(0, 1);   // A1(0)
    STAGE_B(0, 1);   // B1(0)
    STAGE_A(0, 0);   // A0(0)
    STAGE_B(0, 0);   // B0(0)
    STAGE_A(1, 0);   // A0(1)
    STAGE_B(1, 1);   // B1(1)

    f32x4 acc[8][4];
#pragma unroll
    for (int i = 0; i < 8; ++i)
#pragma unroll
        for (int j = 0; j < 4; ++j) { acc[i][j][0] = 0.f; acc[i][j][1] = 0.f; acc[i][j][2] = 0.f; acc[i][j][3] = 0.f; }

    half8 af[4][2], bf[2][2];

    // all tile-0 halves landed (own loads), then collective visibility
    WAITVM(4);
    BAR();

#pragma unroll 1
    for (int kt = 0; kt < NT; ++kt) {
        const int cur = kt & 1;
        // ---- phase 1: quadrant (mh0, nh0) ----
        READ_A(0); READ_B(0);
        STAGE_A(kt + 1, 1);                      // A1(kt+1) -> buf[cur^1]
        BAR(); DO_MFMA(0, 0); BAR();
        // ---- phase 2: quadrant (mh0, nh1), reuse af ----
        READ_B(1);
        STAGE_B(kt + 1, 0);                      // B0(kt+1) -> buf[cur^1]
        BAR(); DO_MFMA(0, 1); BAR();
        // ---- phase 3: quadrant (mh1, nh1), reuse bf ----
        READ_A(1);
        STAGE_A(kt + 2, 0);                      // A0(kt+2) -> buf[cur]
        BAR(); DO_MFMA(1, 1); BAR();
        // ---- phase 4: quadrant (mh1, nh0), reuse af ----
        READ_B(0);
        STAGE_B(kt + 2, 1);                      // B1(kt+2) -> buf[cur]
        if (kt < NT - 2) WAITVM(4);              // retire all of tile kt+1
        else             WAITVM(0);              // tail: kt+2 stages skipped
        BAR(); DO_MFMA(1, 0); BAR();
    }

    float bvv[4];
#pragma unroll
    for (int j = 0; j < 4; ++j) bvv[j] = bia[n0 + wn + 16 * j + l15];

#pragma unroll
    for (int i = 0; i < 8; ++i)
#pragma unroll
        for (int j = 0; j < 4; ++j)
#pragma unroll
            for (int r = 0; r < 4; ++r) {
                const int m = m0 + wm + 16 * i + 4 * lg + r;
                const int n = n0 + wn + 16 * j + l15;
                const float val = acc[i][j][r] + bvv[j];
                if (QKV) {
                    const int bb = m >> 11, ss = m & 2047, hh = n >> 6, hd = n & 63;
                    if (z < 2)   // Q, K: [bh][s][hd]
                        ((_Float16*)C)[((size_t)(bb * NH + hh) * SEQ + ss) * HD + hd] = (_Float16)val;
                    else         // V: transposed [bh][d][s]
                        ((_Float16*)C)[((size_t)(bb * NH + hh) * HD + hd) * SEQ + ss] = (_Float16)val;
                } else {
                    ((float*)C)[(size_t)m * 1024 + n] = val;
                }
            }
#undef STAGE_A
#undef STAGE_B
#undef READ_A
#undef READ_B
#undef DO_MFMA
#undef BAR
#undef WAITVM
}

// ---------------------------------------------------------------------------
// Causal flash attention v4b (unchanged from round-8 proven version).
// ---------------------------------------------------------------------------
__global__ __launch_bounds__(256, 4) void attn_fwd_mfma(
    const _Float16* __restrict__ Q, const _Float16* __restrict__ K,
    const _Float16* __restrict__ Vt, _Float16* __restrict__ O)
{
    __shared__ _Float16 Ks[64][80];
    __shared__ _Float16 Vs[64][80];
    __shared__ _Float16 Ps[4][16][80];

    const int tid  = threadIdx.x;
    const int w    = tid >> 6;
    const int lane = tid & 63;
    const int l15  = lane & 15;
    const int lg   = lane >> 4;

    const int bh = blockIdx.y;
    const int b  = bh >> 4, h = bh & 15;

    const _Float16* Qb  = Q  + (size_t)bh * SEQ * HD;
    const _Float16* Kb  = K  + (size_t)bh * SEQ * HD;   // [s][d]
    const _Float16* Vtb = Vt + (size_t)bh * HD * SEQ;   // [d][s]

    const int srow = tid >> 3;
    const int scol = (tid & 7) * 8;

    for (int pass = 0; pass < 2; ++pass) {
        const int qt = pass ? (int)blockIdx.x : (31 - (int)blockIdx.x);
        const int q0 = qt * 64;
        const int ntiles = qt + 1;

        half8 qa[2];
        {
            const _Float16* qp = Qb + (size_t)(q0 + 16 * w + l15) * HD + 8 * lg;
            qa[0] = *(const half8*)(qp);
            qa[1] = *(const half8*)(qp + 32);
#pragma unroll
            for (int c = 0; c < 2; ++c)
#pragma unroll
                for (int j = 0; j < 8; ++j)
                    qa[c][j] = (_Float16)((float)qa[c][j] * 0.18033688f);
        }

        f32x4 o_[4];
#pragma unroll
        for (int ft = 0; ft < 4; ++ft) { o_[ft][0] = 0.f; o_[ft][1] = 0.f; o_[ft][2] = 0.f; o_[ft][3] = 0.f; }
        float lp[4] = {0.f, 0.f, 0.f, 0.f};

        half8 kreg[2], vreg[2];
#pragma unroll
        for (int j = 0; j < 2; ++j) {
            kreg[j] = *(const half8*)(Kb  + (size_t)(srow + 32 * j) * HD + scol);
            vreg[j] = *(const half8*)(Vtb + (size_t)(srow + 32 * j) * SEQ + scol);
        }

        for (int kt = 0; kt < ntiles; ++kt) {
            __syncthreads();
#pragma unroll
            for (int j = 0; j < 2; ++j) {
                *(half8*)&Ks[srow + 32 * j][scol] = kreg[j];
                *(half8*)&Vs[srow + 32 * j][scol] = vreg[j];
            }
            __syncthreads();

            if (kt + 1 < ntiles) {
                const int k0 = (kt + 1) * 64;
#pragma unroll
                for (int j = 0; j < 2; ++j) {
                    kreg[j] = *(const half8*)(Kb  + (size_t)(k0 + srow + 32 * j) * HD + scol);
                    vreg[j] = *(const half8*)(Vtb + (size_t)(srow + 32 * j) * SEQ + k0 + scol);
                }
            }

            // ---- S = Q K^T : 8 MFMAs ----
            f32x4 s[4];
#pragma unroll
            for (int f = 0; f < 4; ++f) { s[f][0] = 0.f; s[f][1] = 0.f; s[f][2] = 0.f; s[f][3] = 0.f; }
#pragma unroll
            for (int c = 0; c < 2; ++c)
#pragma unroll
                for (int f = 0; f < 4; ++f) {
                    half8 kb = *(const half8*)&Ks[16 * f + l15][32 * c + 8 * lg];
                    s[f] = __builtin_amdgcn_mfma_f32_16x16x32_f16(qa[c], kb, s[f], 0, 0, 0);
                }

            // ---- p = exp2(s), mask, stash ----
            const bool dg = (kt == qt);
#pragma unroll
            for (int f = 0; f < 4; ++f)
#pragma unroll
                for (int r = 0; r < 4; ++r) {
                    float p = EXP2(s[f][r]);
                    if (dg && (16 * f + l15 > 16 * w + 4 * lg + r)) p = 0.f;
                    lp[r] += p;
                    Ps[w][4 * lg + r][16 * f + l15] = (_Float16)p;
                }

            // ---- O += P V : 8 MFMAs ----
            half8 pa[2];
            pa[0] = *(const half8*)&Ps[w][l15][8 * lg];
            pa[1] = *(const half8*)&Ps[w][l15][32 + 8 * lg];
#pragma unroll
            for (int c = 0; c < 2; ++c)
#pragma unroll
                for (int ft = 0; ft < 4; ++ft) {
                    half8 vb = *(const half8*)&Vs[16 * ft + l15][32 * c + 8 * lg];
                    o_[ft] = __builtin_amdgcn_mfma_f32_16x16x32_f16(pa[c], vb, o_[ft], 0, 0, 0);
                }
        }

        // ---- epilogue ----
#pragma unroll
        for (int r = 0; r < 4; ++r) {
            float rs = lp[r];
            rs += __shfl_xor(rs, 1);
            rs += __shfl_xor(rs, 2);
            rs += __shfl_xor(rs, 4);
            rs += __shfl_xor(rs, 8);
            const float inv = 1.0f / rs;
            _Float16* orow = O + (size_t)(b * SEQ + q0 + 16 * w + 4 * lg + r) * D_MODEL + h * HD + l15;
#pragma unroll
            for (int ft = 0; ft < 4; ++ft) orow[16 * ft] = (_Float16)(o_[ft][r] * inv);
        }
        __syncthreads();  // Ps/Ks/Vs reuse across passes
    }
}

// ---------------------------------------------------------------------------
extern "C" void kernel_launch(void* const* d_in, const int* in_sizes, int n_in,
                              void* d_out, int out_size, void* d_ws, size_t ws_size,
                              hipStream_t stream)
{
    const float* x  = (const float*)d_in[0];
    const float* wq = (const float*)d_in[1];
    const float* bq = (const float*)d_in[2];
    const float* wk = (const float*)d_in[3];
    const float* bk = (const float*)d_in[4];
    const float* wv = (const float*)d_in[5];
    const float* bv = (const float*)d_in[6];
    const float* wo = (const float*)d_in[7];
    const float* bo = (const float*)d_in[8];
    float* out = (float*)d_out;

    const size_t SZ = (size_t)MTOT * D_MODEL;  // 8388608
    const size_t WZ = (size_t)D_MODEL * D_MODEL;

    _Float16* xh  = (_Float16*)d_ws;
    _Float16* wtq = xh + SZ;
    _Float16* wtk = wtq + WZ;
    _Float16* wtv = wtk + WZ;
    _Float16* wto = wtv + WZ;
    _Float16* Qh  = wto + WZ;
    _Float16* Kh  = Qh + SZ;
    _Float16* Vtg = Kh + SZ;   // V, already transposed [bh][d][s]
    _Float16* AOh = Vtg + SZ;  // total ~88 MiB

    // fused prep: x cvt (blocks 0..255) + 4 weight transposes (256..1279)
    prep<<<dim3(1280), 256, 0, stream>>>(x, xh, wq, wk, wv, wo, wtq, wtk, wtv, wto);
    // QKV projection: 256^2-tile 4-phase counted-vmcnt, 384 blocks x 512 thr
    gemm_mfma<1><<<dim3(384), 512, 0, stream>>>(xh, wtq, wtk, wtv, bq, bk, bv, Qh, Kh, Vtg);
    attn_fwd_mfma<<<dim3(16, BATCH * NH), 256, 0, stream>>>(Qh, Kh, Vtg, AOh);
    // output projection: 256^2-tile 4-phase counted-vmcnt, 128 blocks x 512 thr
    gemm_mfma<0><<<dim3(128), 512, 0, stream>>>(AOh, wto, wto, wto, bo, bo, bo, out, out, out);
}

// Round 5
// 284.221 us; speedup vs baseline: 1.0355x; 1.0355x over previous
//
#include <hip/hip_runtime.h>
#include <cstddef>

#define D_MODEL 1024
#define NH 16
#define HD 64
#define BATCH 4
#define SEQ 2048
#define MTOT (BATCH * SEQ)  // 8192

typedef _Float16 half8 __attribute__((ext_vector_type(8)));
typedef _Float16 half4v __attribute__((ext_vector_type(4)));
typedef float f32x4 __attribute__((ext_vector_type(4)));

#if __has_builtin(__builtin_amdgcn_exp2f)
#define EXP2(x) __builtin_amdgcn_exp2f(x)
#else
#define EXP2(x) __expf((x)*0.69314718056f)
#endif

// async global->LDS, 16B per lane. LDS dest must be wave-uniform base (+lane*16 implicit).
#define ASYNC_COPY16(g, l)                                                    \
    __builtin_amdgcn_global_load_lds(                                         \
        (__attribute__((address_space(1))) const void*)(g),                   \
        (__attribute__((address_space(3))) void*)(l), 16, 0, 0)

// Swizzled LDS fragment read: logical element (R, CH f16-cols) of a [*][64]
// f16 tile lives at byte R*128 + ((CH*2) ^ ((R&7)<<4)).  Staging applies the
// inverse permutation on the GLOBAL source address (linear dest + inverse-swz
// source + swz read), so a wave's 64 lanes reading one column-slice across 16
// rows land on distinct 16B slots -> 2-way (free) instead of 16-way.
#define LDSFRAG(S, R, CH)                                                     \
    (*(const half8*)((const char*)(S) + ((R) << 7) +                          \
                     ((((CH) << 1)) ^ (((R) & 7) << 4))))

// ---------------------------------------------------------------------------
// Fused prep (unchanged):
//   blocks 0..255    : x fp32 -> f16 (4096 half8 chunks per block)
//   blocks 256..1279 : 4 weight matrices fp32 [k][n] -> f16 transposed [n][k]
// ---------------------------------------------------------------------------
__global__ __launch_bounds__(256) void prep(
    const float* __restrict__ x, _Float16* __restrict__ xh,
    const float* __restrict__ W0, const float* __restrict__ W1,
    const float* __restrict__ W2, const float* __restrict__ W3,
    _Float16* __restrict__ T0, _Float16* __restrict__ T1,
    _Float16* __restrict__ T2, _Float16* __restrict__ T3)
{
    __shared__ float T[64][65];
    const int bid = blockIdx.x;
    if (bid < 256) {
        const size_t base = (size_t)bid * 4096 + threadIdx.x;
#pragma unroll
        for (int it = 0; it < 16; ++it) {
            const size_t i = base + (size_t)it * 256;
            const float4* p = (const float4*)x + 2 * i;
            float4 a = p[0], b = p[1];
            half8 h;
            h[0] = (_Float16)a.x; h[1] = (_Float16)a.y; h[2] = (_Float16)a.z; h[3] = (_Float16)a.w;
            h[4] = (_Float16)b.x; h[5] = (_Float16)b.y; h[6] = (_Float16)b.z; h[7] = (_Float16)b.w;
            *((half8*)xh + i) = h;
        }
    } else {
        const int t = bid - 256;
        const int mtx = t >> 8;
        const float* W = (mtx == 0) ? W0 : (mtx == 1) ? W1 : (mtx == 2) ? W2 : W3;
        _Float16*   Wt = (mtx == 0) ? T0 : (mtx == 1) ? T1 : (mtx == 2) ? T2 : T3;
        const int tile = t & 255;
        const int k0 = (tile >> 4) * 64, n0 = (tile & 15) * 64;
        const int r = threadIdx.x >> 4, c4 = (threadIdx.x & 15) * 4;

#pragma unroll
        for (int i = 0; i < 4; ++i) {
            float4 v = *(const float4*)(W + (size_t)(k0 + r + 16 * i) * 1024 + n0 + c4);
            T[r + 16 * i][c4 + 0] = v.x; T[r + 16 * i][c4 + 1] = v.y;
            T[r + 16 * i][c4 + 2] = v.z; T[r + 16 * i][c4 + 3] = v.w;
        }
        __syncthreads();
#pragma unroll
        for (int i = 0; i < 4; ++i) {
            const int n = r + 16 * i;
            half4v h;
            h[0] = (_Float16)T[c4 + 0][n]; h[1] = (_Float16)T[c4 + 1][n];
            h[2] = (_Float16)T[c4 + 2][n]; h[3] = (_Float16)T[c4 + 3][n];
            *(half4v*)(Wt + (size_t)(n0 + n) * 1024 + k0 + c4) = h;
        }
    }
}

// ---------------------------------------------------------------------------
// MFMA f16 GEMM — EXACT round-1 version (proven 80.5 us QKV / 0 conflicts):
// m97-structure, global_load_lds staging, linear [128][64] LDS (BK=64),
// both-sides XOR swizzle, 2 barriers per K-step, 128^2 tile, 4 waves,
// 32 KB LDS -> ~3 blocks/CU. XCD-affinity 1D grid.
// QKV=1: c = L>>6: z = c/8 in {Q,K,V}, x-block = c%8.
//        z in {0,1}: f16 [bh][s][hd]; z==2: V transposed [bh][d][s].
// QKV=0: single output, f32 [m][n]. c = L>>6 = x-block.
// ---------------------------------------------------------------------------
template <int QKV>
__global__ __launch_bounds__(256) void gemm_mfma(
    const _Float16* __restrict__ A,
    const _Float16* __restrict__ Bt0, const _Float16* __restrict__ Bt1, const _Float16* __restrict__ Bt2,
    const float* __restrict__ bi0, const float* __restrict__ bi1, const float* __restrict__ bi2,
    void* __restrict__ C0, void* __restrict__ C1, void* __restrict__ C2)
{
    const int L = blockIdx.x;
    const int y = L & 63;
    const int c_ = L >> 6;
    const int z  = QKV ? (c_ >> 3) : 0;
    const int xb = QKV ? (c_ & 7) : c_;

    const _Float16* Bt = (z == 0) ? Bt0 : (z == 1) ? Bt1 : Bt2;
    const float*   bia = (z == 0) ? bi0 : (z == 1) ? bi1 : bi2;
    void*            C = (z == 0) ? C0  : (z == 1) ? C1  : C2;

    __shared__ _Float16 As[128][64];
    __shared__ _Float16 Bs[128][64];

    const int tid  = threadIdx.x;
    const int w    = tid >> 6;
    const int lane = tid & 63;
    const int l15  = lane & 15;
    const int lg   = lane >> 4;
    const int m0 = y * 128;
    const int n0 = xb * 128;
    const int wm = (w >> 1) * 64, wn = (w & 1) * 64;

    const int rsub = lane >> 3;                       // 0..7
    const int cswz = ((lane & 7) ^ rsub) * 8;         // halves

    const _Float16* gA = A  + (size_t)(m0 + 32 * w + rsub) * 1024 + cswz;
    const _Float16* gB = Bt + (size_t)(n0 + 32 * w + rsub) * 1024 + cswz;
    char* lA = (char*)As + (size_t)(w * 4) * 1024;
    char* lB = (char*)Bs + (size_t)(w * 4) * 1024;

    f32x4 acc[4][4];
#pragma unroll
    for (int i = 0; i < 4; ++i)
#pragma unroll
        for (int j = 0; j < 4; ++j) { acc[i][j][0] = 0.f; acc[i][j][1] = 0.f; acc[i][j][2] = 0.f; acc[i][j][3] = 0.f; }

    for (int kt = 0; kt < 16; ++kt) {
        const int k0 = kt * 64;
        __syncthreads();  // all reads of previous tile done before overwrite
#pragma unroll
        for (int i = 0; i < 4; ++i) {
            ASYNC_COPY16(gA + (size_t)(8 * i) * 1024 + k0, lA + i * 1024);
            ASYNC_COPY16(gB + (size_t)(8 * i) * 1024 + k0, lB + i * 1024);
        }
        __syncthreads();  // compiler drains vmcnt(0) before s_barrier -> tile visible

#pragma unroll
        for (int c = 0; c < 2; ++c) {
            half8 af[4], bf[4];
#pragma unroll
            for (int i = 0; i < 4; ++i) af[i] = LDSFRAG(As, wm + 16 * i + l15, 32 * c + 8 * lg);
#pragma unroll
            for (int j = 0; j < 4; ++j) bf[j] = LDSFRAG(Bs, wn + 16 * j + l15, 32 * c + 8 * lg);
#pragma unroll
            for (int i = 0; i < 4; ++i)
#pragma unroll
                for (int j = 0; j < 4; ++j)
                    acc[i][j] = __builtin_amdgcn_mfma_f32_16x16x32_f16(af[i], bf[j], acc[i][j], 0, 0, 0);
        }
    }

    float bvv[4];
#pragma unroll
    for (int j = 0; j < 4; ++j) bvv[j] = bia[n0 + wn + 16 * j + l15];

#pragma unroll
    for (int i = 0; i < 4; ++i)
#pragma unroll
        for (int j = 0; j < 4; ++j)
#pragma unroll
            for (int r = 0; r < 4; ++r) {
                const int m = m0 + wm + 16 * i + 4 * lg + r;
                const int n = n0 + wn + 16 * j + l15;
                const float val = acc[i][j][r] + bvv[j];
                if (QKV) {
                    const int bb = m >> 11, ss = m & 2047, hh = n >> 6, hd = n & 63;
                    if (z < 2)   // Q, K: [bh][s][hd]
                        ((_Float16*)C)[((size_t)(bb * NH + hh) * SEQ + ss) * HD + hd] = (_Float16)val;
                    else         // V: transposed [bh][d][s]
                        ((_Float16*)C)[((size_t)(bb * NH + hh) * HD + hd) * SEQ + ss] = (_Float16)val;
                } else {
                    ((float*)C)[(size_t)m * 1024 + n] = val;
                }
            }
}

// ---------------------------------------------------------------------------
// Causal flash attention v5: round-4 change — K/V staging converted from
// reg-prefetch + ds_write (pitch-80, 4-way read conflicts) to
// global_load_lds + both-sides XOR swizzle (linear [64][64] dbuf LDS,
// conflict-free ds_read_b128), minimum-2-phase overlap: next tile's stage
// issued right after the collective barrier, so K/V HBM latency hides under
// QK^T/softmax/PV. LDS 42 KB -> 3 blocks/CU. Softmax/Ps/epilogue unchanged.
// ---------------------------------------------------------------------------
__global__ __launch_bounds__(256, 3) void attn_fwd_mfma(
    const _Float16* __restrict__ Q, const _Float16* __restrict__ K,
    const _Float16* __restrict__ Vt, _Float16* __restrict__ O)
{
    __shared__ _Float16 Ks[2][64][64];
    __shared__ _Float16 Vs[2][64][64];
    __shared__ _Float16 Ps[4][16][80];

    const int tid  = threadIdx.x;
    const int w    = tid >> 6;
    const int lane = tid & 63;
    const int l15  = lane & 15;
    const int lg   = lane >> 4;

    const int bh = blockIdx.y;
    const int b  = bh >> 4, h = bh & 15;

    const _Float16* Qb  = Q  + (size_t)bh * SEQ * HD;
    const _Float16* Kb  = K  + (size_t)bh * SEQ * HD;   // [s][d]
    const _Float16* Vtb = Vt + (size_t)bh * HD * SEQ;   // [d][s]

    const int rsub = lane >> 3;                       // 0..7
    const int cswz = ((lane & 7) ^ rsub) * 8;         // inverse-swz f16 col

    for (int pass = 0; pass < 2; ++pass) {
        const int qt = pass ? (int)blockIdx.x : (31 - (int)blockIdx.x);
        const int q0 = qt * 64;
        const int ntiles = qt + 1;

        // ---- stage tile 0 (K: rows contiguous 64-f16; V: rows stride SEQ) ----
#pragma unroll
        for (int i = 0; i < 2; ++i) {
            const int c = 2 * w + i;                  // 0..7 -> rows c*8..c*8+7
            ASYNC_COPY16(Kb  + (size_t)(c * 8 + rsub) * HD  + cswz, &Ks[0][c * 8][0]);
            ASYNC_COPY16(Vtb + (size_t)(c * 8 + rsub) * SEQ + cswz, &Vs[0][c * 8][0]);
        }

        // ---- Q load + scale (overlaps tile-0 staging latency) ----
        half8 qa[2];
        {
            const _Float16* qp = Qb + (size_t)(q0 + 16 * w + l15) * HD + 8 * lg;
            qa[0] = *(const half8*)(qp);
            qa[1] = *(const half8*)(qp + 32);
#pragma unroll
            for (int c = 0; c < 2; ++c)
#pragma unroll
                for (int j = 0; j < 8; ++j)
                    qa[c][j] = (_Float16)((float)qa[c][j] * 0.18033688f);
        }

        f32x4 o_[4];
#pragma unroll
        for (int ft = 0; ft < 4; ++ft) { o_[ft][0] = 0.f; o_[ft][1] = 0.f; o_[ft][2] = 0.f; o_[ft][3] = 0.f; }
        float lp[4] = {0.f, 0.f, 0.f, 0.f};

        for (int kt = 0; kt < ntiles; ++kt) {
            const int cur = kt & 1;
            // tile kt landed (own loads), then collective visibility
            asm volatile("s_waitcnt vmcnt(0)" ::: "memory");
            __builtin_amdgcn_s_barrier();

            // prefetch tile kt+1 into the other buffer (write-after-read safe:
            // buf[cur^1]'s tile kt-1 reads drained before every wave reached
            // the barrier above)
            if (kt + 1 < ntiles) {
                const int k0 = (kt + 1) * 64;
#pragma unroll
                for (int i = 0; i < 2; ++i) {
                    const int c = 2 * w + i;
                    ASYNC_COPY16(Kb  + (size_t)(k0 + c * 8 + rsub) * HD + cswz,
                                 &Ks[cur ^ 1][c * 8][0]);
                    ASYNC_COPY16(Vtb + (size_t)(c * 8 + rsub) * SEQ + k0 + cswz,
                                 &Vs[cur ^ 1][c * 8][0]);
                }
            }

            // ---- S = Q K^T : 8 MFMAs (swizzled conflict-free reads) ----
            f32x4 s[4];
#pragma unroll
            for (int f = 0; f < 4; ++f) { s[f][0] = 0.f; s[f][1] = 0.f; s[f][2] = 0.f; s[f][3] = 0.f; }
#pragma unroll
            for (int c = 0; c < 2; ++c)
#pragma unroll
                for (int f = 0; f < 4; ++f) {
                    half8 kb = LDSFRAG(&Ks[cur][0][0], 16 * f + l15, 32 * c + 8 * lg);
                    s[f] = __builtin_amdgcn_mfma_f32_16x16x32_f16(qa[c], kb, s[f], 0, 0, 0);
                }

            // ---- p = exp2(s), mask, stash ----
            const bool dg = (kt == qt);
#pragma unroll
            for (int f = 0; f < 4; ++f)
#pragma unroll
                for (int r = 0; r < 4; ++r) {
                    float p = EXP2(s[f][r]);
                    if (dg && (16 * f + l15 > 16 * w + 4 * lg + r)) p = 0.f;
                    lp[r] += p;
                    Ps[w][4 * lg + r][16 * f + l15] = (_Float16)p;
                }

            // ---- O += P V : 8 MFMAs ----
            half8 pa[2];
            pa[0] = *(const half8*)&Ps[w][l15][8 * lg];
            pa[1] = *(const half8*)&Ps[w][l15][32 + 8 * lg];
#pragma unroll
            for (int c = 0; c < 2; ++c)
#pragma unroll
                for (int ft = 0; ft < 4; ++ft) {
                    half8 vb = LDSFRAG(&Vs[cur][0][0], 16 * ft + l15, 32 * c + 8 * lg);
                    o_[ft] = __builtin_amdgcn_mfma_f32_16x16x32_f16(pa[c], vb, o_[ft], 0, 0, 0);
                }
        }

        // ---- epilogue ----
#pragma unroll
        for (int r = 0; r < 4; ++r) {
            float rs = lp[r];
            rs += __shfl_xor(rs, 1);
            rs += __shfl_xor(rs, 2);
            rs += __shfl_xor(rs, 4);
            rs += __shfl_xor(rs, 8);
            const float inv = 1.0f / rs;
            _Float16* orow = O + (size_t)(b * SEQ + q0 + 16 * w + 4 * lg + r) * D_MODEL + h * HD + l15;
#pragma unroll
            for (int ft = 0; ft < 4; ++ft) orow[16 * ft] = (_Float16)(o_[ft][r] * inv);
        }
        __syncthreads();  // Ps/Ks/Vs reuse across passes
    }
}

// ---------------------------------------------------------------------------
extern "C" void kernel_launch(void* const* d_in, const int* in_sizes, int n_in,
                              void* d_out, int out_size, void* d_ws, size_t ws_size,
                              hipStream_t stream)
{
    const float* x  = (const float*)d_in[0];
    const float* wq = (const float*)d_in[1];
    const float* bq = (const float*)d_in[2];
    const float* wk = (const float*)d_in[3];
    const float* bk = (const float*)d_in[4];
    const float* wv = (const float*)d_in[5];
    const float* bv = (const float*)d_in[6];
    const float* wo = (const float*)d_in[7];
    const float* bo = (const float*)d_in[8];
    float* out = (float*)d_out;

    const size_t SZ = (size_t)MTOT * D_MODEL;  // 8388608
    const size_t WZ = (size_t)D_MODEL * D_MODEL;

    _Float16* xh  = (_Float16*)d_ws;
    _Float16* wtq = xh + SZ;
    _Float16* wtk = wtq + WZ;
    _Float16* wtv = wtk + WZ;
    _Float16* wto = wtv + WZ;
    _Float16* Qh  = wto + WZ;
    _Float16* Kh  = Qh + SZ;
    _Float16* Vtg = Kh + SZ;   // V, already transposed [bh][d][s]
    _Float16* AOh = Vtg + SZ;  // total ~88 MiB

    // fused prep: x cvt (blocks 0..255) + 4 weight transposes (256..1279)
    prep<<<dim3(1280), 256, 0, stream>>>(x, xh, wq, wk, wv, wo, wtq, wtk, wtv, wto);
    // QKV projection: XCD-affinity 1D grid (1536 blocks), glds staging
    gemm_mfma<1><<<dim3(1536), 256, 0, stream>>>(xh, wtq, wtk, wtv, bq, bk, bv, Qh, Kh, Vtg);
    attn_fwd_mfma<<<dim3(16, BATCH * NH), 256, 0, stream>>>(Qh, Kh, Vtg, AOh);
    // output projection: XCD-affinity 1D grid (512 blocks)
    gemm_mfma<0><<<dim3(512), 256, 0, stream>>>(AOh, wto, wto, wto, bo, bo, bo, out, out, out);
}

// Round 6
// 277.111 us; speedup vs baseline: 1.0621x; 1.0257x over previous
//
#include <hip/hip_runtime.h>
#include <cstddef>

#define D_MODEL 1024
#define NH 16
#define HD 64
#define BATCH 4
#define SEQ 2048
#define MTOT (BATCH * SEQ)  // 8192

typedef _Float16 half8 __attribute__((ext_vector_type(8)));
typedef _Float16 half4v __attribute__((ext_vector_type(4)));
typedef float f32x4 __attribute__((ext_vector_type(4)));

#if __has_builtin(__builtin_amdgcn_exp2f)
#define EXP2(x) __builtin_amdgcn_exp2f(x)
#else
#define EXP2(x) __expf((x)*0.69314718056f)
#endif

// async global->LDS, 16B per lane. LDS dest must be wave-uniform base (+lane*16 implicit).
#define ASYNC_COPY16(g, l)                                                    \
    __builtin_amdgcn_global_load_lds(                                         \
        (__attribute__((address_space(1))) const void*)(g),                   \
        (__attribute__((address_space(3))) void*)(l), 16, 0, 0)

// Swizzled LDS fragment read: logical element (R, CH f16-cols) of a [*][64]
// f16 tile lives at byte R*128 + ((CH*2) ^ ((R&7)<<4)).  Staging applies the
// inverse permutation on the GLOBAL source address (linear dest + inverse-swz
// source + swz read), so a wave's 64 lanes reading one column-slice across 16
// rows land on distinct 16B slots -> 2-way (free) instead of 16-way.
#define LDSFRAG(S, R, CH)                                                     \
    (*(const half8*)((const char*)(S) + ((R) << 7) +                          \
                     ((((CH) << 1)) ^ (((R) & 7) << 4))))

// ---------------------------------------------------------------------------
// Fused prep (unchanged):
//   blocks 0..255    : x fp32 -> f16 (4096 half8 chunks per block)
//   blocks 256..1279 : 4 weight matrices fp32 [k][n] -> f16 transposed [n][k]
// ---------------------------------------------------------------------------
__global__ __launch_bounds__(256) void prep(
    const float* __restrict__ x, _Float16* __restrict__ xh,
    const float* __restrict__ W0, const float* __restrict__ W1,
    const float* __restrict__ W2, const float* __restrict__ W3,
    _Float16* __restrict__ T0, _Float16* __restrict__ T1,
    _Float16* __restrict__ T2, _Float16* __restrict__ T3)
{
    __shared__ float T[64][65];
    const int bid = blockIdx.x;
    if (bid < 256) {
        const size_t base = (size_t)bid * 4096 + threadIdx.x;
#pragma unroll
        for (int it = 0; it < 16; ++it) {
            const size_t i = base + (size_t)it * 256;
            const float4* p = (const float4*)x + 2 * i;
            float4 a = p[0], b = p[1];
            half8 h;
            h[0] = (_Float16)a.x; h[1] = (_Float16)a.y; h[2] = (_Float16)a.z; h[3] = (_Float16)a.w;
            h[4] = (_Float16)b.x; h[5] = (_Float16)b.y; h[6] = (_Float16)b.z; h[7] = (_Float16)b.w;
            *((half8*)xh + i) = h;
        }
    } else {
        const int t = bid - 256;
        const int mtx = t >> 8;
        const float* W = (mtx == 0) ? W0 : (mtx == 1) ? W1 : (mtx == 2) ? W2 : W3;
        _Float16*   Wt = (mtx == 0) ? T0 : (mtx == 1) ? T1 : (mtx == 2) ? T2 : T3;
        const int tile = t & 255;
        const int k0 = (tile >> 4) * 64, n0 = (tile & 15) * 64;
        const int r = threadIdx.x >> 4, c4 = (threadIdx.x & 15) * 4;

#pragma unroll
        for (int i = 0; i < 4; ++i) {
            float4 v = *(const float4*)(W + (size_t)(k0 + r + 16 * i) * 1024 + n0 + c4);
            T[r + 16 * i][c4 + 0] = v.x; T[r + 16 * i][c4 + 1] = v.y;
            T[r + 16 * i][c4 + 2] = v.z; T[r + 16 * i][c4 + 3] = v.w;
        }
        __syncthreads();
#pragma unroll
        for (int i = 0; i < 4; ++i) {
            const int n = r + 16 * i;
            half4v h;
            h[0] = (_Float16)T[c4 + 0][n]; h[1] = (_Float16)T[c4 + 1][n];
            h[2] = (_Float16)T[c4 + 2][n]; h[3] = (_Float16)T[c4 + 3][n];
            *(half4v*)(Wt + (size_t)(n0 + n) * 1024 + k0 + c4) = h;
        }
    }
}

// ---------------------------------------------------------------------------
// MFMA f16 GEMM — EXACT round-1 version (proven 80.5 us QKV / 0 conflicts):
// m97-structure, global_load_lds staging, linear [128][64] LDS (BK=64),
// both-sides XOR swizzle, 2 barriers per K-step, 128^2 tile, 4 waves,
// 32 KB LDS -> ~3 blocks/CU. XCD-affinity 1D grid.
// QKV=1: c = L>>6: z = c/8 in {Q,K,V}, x-block = c%8.
//        z in {0,1}: f16 [bh][s][hd]; z==2: V transposed [bh][d][s].
// QKV=0: single output, f32 [m][n]. c = L>>6 = x-block.
// ---------------------------------------------------------------------------
template <int QKV>
__global__ __launch_bounds__(256) void gemm_mfma(
    const _Float16* __restrict__ A,
    const _Float16* __restrict__ Bt0, const _Float16* __restrict__ Bt1, const _Float16* __restrict__ Bt2,
    const float* __restrict__ bi0, const float* __restrict__ bi1, const float* __restrict__ bi2,
    void* __restrict__ C0, void* __restrict__ C1, void* __restrict__ C2)
{
    const int L = blockIdx.x;
    const int y = L & 63;
    const int c_ = L >> 6;
    const int z  = QKV ? (c_ >> 3) : 0;
    const int xb = QKV ? (c_ & 7) : c_;

    const _Float16* Bt = (z == 0) ? Bt0 : (z == 1) ? Bt1 : Bt2;
    const float*   bia = (z == 0) ? bi0 : (z == 1) ? bi1 : bi2;
    void*            C = (z == 0) ? C0  : (z == 1) ? C1  : C2;

    __shared__ _Float16 As[128][64];
    __shared__ _Float16 Bs[128][64];

    const int tid  = threadIdx.x;
    const int w    = tid >> 6;
    const int lane = tid & 63;
    const int l15  = lane & 15;
    const int lg   = lane >> 4;
    const int m0 = y * 128;
    const int n0 = xb * 128;
    const int wm = (w >> 1) * 64, wn = (w & 1) * 64;

    const int rsub = lane >> 3;                       // 0..7
    const int cswz = ((lane & 7) ^ rsub) * 8;         // halves

    const _Float16* gA = A  + (size_t)(m0 + 32 * w + rsub) * 1024 + cswz;
    const _Float16* gB = Bt + (size_t)(n0 + 32 * w + rsub) * 1024 + cswz;
    char* lA = (char*)As + (size_t)(w * 4) * 1024;
    char* lB = (char*)Bs + (size_t)(w * 4) * 1024;

    f32x4 acc[4][4];
#pragma unroll
    for (int i = 0; i < 4; ++i)
#pragma unroll
        for (int j = 0; j < 4; ++j) { acc[i][j][0] = 0.f; acc[i][j][1] = 0.f; acc[i][j][2] = 0.f; acc[i][j][3] = 0.f; }

    for (int kt = 0; kt < 16; ++kt) {
        const int k0 = kt * 64;
        __syncthreads();  // all reads of previous tile done before overwrite
#pragma unroll
        for (int i = 0; i < 4; ++i) {
            ASYNC_COPY16(gA + (size_t)(8 * i) * 1024 + k0, lA + i * 1024);
            ASYNC_COPY16(gB + (size_t)(8 * i) * 1024 + k0, lB + i * 1024);
        }
        __syncthreads();  // compiler drains vmcnt(0) before s_barrier -> tile visible

#pragma unroll
        for (int c = 0; c < 2; ++c) {
            half8 af[4], bf[4];
#pragma unroll
            for (int i = 0; i < 4; ++i) af[i] = LDSFRAG(As, wm + 16 * i + l15, 32 * c + 8 * lg);
#pragma unroll
            for (int j = 0; j < 4; ++j) bf[j] = LDSFRAG(Bs, wn + 16 * j + l15, 32 * c + 8 * lg);
#pragma unroll
            for (int i = 0; i < 4; ++i)
#pragma unroll
                for (int j = 0; j < 4; ++j)
                    acc[i][j] = __builtin_amdgcn_mfma_f32_16x16x32_f16(af[i], bf[j], acc[i][j], 0, 0, 0);
        }
    }

    float bvv[4];
#pragma unroll
    for (int j = 0; j < 4; ++j) bvv[j] = bia[n0 + wn + 16 * j + l15];

#pragma unroll
    for (int i = 0; i < 4; ++i)
#pragma unroll
        for (int j = 0; j < 4; ++j)
#pragma unroll
            for (int r = 0; r < 4; ++r) {
                const int m = m0 + wm + 16 * i + 4 * lg + r;
                const int n = n0 + wn + 16 * j + l15;
                const float val = acc[i][j][r] + bvv[j];
                if (QKV) {
                    const int bb = m >> 11, ss = m & 2047, hh = n >> 6, hd = n & 63;
                    if (z < 2)   // Q, K: [bh][s][hd]
                        ((_Float16*)C)[((size_t)(bb * NH + hh) * SEQ + ss) * HD + hd] = (_Float16)val;
                    else         // V: transposed [bh][d][s]
                        ((_Float16*)C)[((size_t)(bb * NH + hh) * HD + hd) * SEQ + ss] = (_Float16)val;
                } else {
                    ((float*)C)[(size_t)m * 1024 + n] = val;
                }
            }
}

// ---------------------------------------------------------------------------
// Causal flash attention v6 (round-5 fixes):
//  (1) bh->XCD affinity: 1D grid, bid = qt*64 + bh; since 64%8==0, bid%8 =
//      bh%8 -> all 16 q-tile blocks of a bh land on one XCD; its L2 holds the
//      live K/V working set (round-5 PMC: FETCH 191 MB = 3x over-fetch from
//      cross-XCD replication).
//  (2) split counted vmcnt: K staged before V; per tile: vmcnt(2) [K landed,
//      V in flight] + barrier -> QK^T/softmax (prefetch kt+1: K then V) ->
//      vmcnt(4) [V(kt) landed, kt+1 in flight] + barrier -> PV.  V's HBM/L2
//      latency hides under QK^T+softmax instead of sitting on the critical
//      path (round-5: single vmcnt(0) exposed full latency per tile).
//      Invariant entering tile kt: outstanding = [K(kt)x2, V(kt)x2]; tail
//      tile uses vmcnt(0).  Q loads issue BEFORE staging so the compiler's
//      counted wait for the Q-scale retires only Q.
//  WAR safety: prefetch targets buf[cur^1]; its last reads (tile kt-1)
//  completed >=1 barrier before the prefetch issues.
// ---------------------------------------------------------------------------
__global__ __launch_bounds__(256, 3) void attn_fwd_mfma(
    const _Float16* __restrict__ Q, const _Float16* __restrict__ K,
    const _Float16* __restrict__ Vt, _Float16* __restrict__ O)
{
    __shared__ _Float16 Ks[2][64][64];
    __shared__ _Float16 Vs[2][64][64];
    __shared__ _Float16 Ps[4][16][80];

    const int tid  = threadIdx.x;
    const int w    = tid >> 6;
    const int lane = tid & 63;
    const int l15  = lane & 15;
    const int lg   = lane >> 4;

    const int bid = blockIdx.x;
    const int bh  = bid & 63;          // bid%8 == bh%8 -> XCD affinity
    const int qtb = bid >> 6;          // 0..15
    const int b  = bh >> 4, h = bh & 15;

    const _Float16* Qb  = Q  + (size_t)bh * SEQ * HD;
    const _Float16* Kb  = K  + (size_t)bh * SEQ * HD;   // [s][d]
    const _Float16* Vtb = Vt + (size_t)bh * HD * SEQ;   // [d][s]

    const int rsub = lane >> 3;                       // 0..7
    const int cswz = ((lane & 7) ^ rsub) * 8;         // inverse-swz f16 col

#define WAITVM(n_) asm volatile("s_waitcnt vmcnt(" #n_ ")" ::: "memory")

    for (int pass = 0; pass < 2; ++pass) {
        const int qt = pass ? qtb : (31 - qtb);
        const int q0 = qt * 64;
        const int ntiles = qt + 1;

        // ---- Q raw loads first (so the scale's wait retires only these) ----
        const _Float16* qp = Qb + (size_t)(q0 + 16 * w + l15) * HD + 8 * lg;
        half8 q0r = *(const half8*)(qp);
        half8 q1r = *(const half8*)(qp + 32);

        // ---- stage tile 0: all K issues, then all V issues ----
#pragma unroll
        for (int i = 0; i < 2; ++i) {
            const int c = 2 * w + i;                  // rows c*8..c*8+7
            ASYNC_COPY16(Kb + (size_t)(c * 8 + rsub) * HD + cswz, &Ks[0][c * 8][0]);
        }
#pragma unroll
        for (int i = 0; i < 2; ++i) {
            const int c = 2 * w + i;
            ASYNC_COPY16(Vtb + (size_t)(c * 8 + rsub) * SEQ + cswz, &Vs[0][c * 8][0]);
        }

        // ---- Q scale (compiler inserts counted wait retiring Q loads) ----
        half8 qa[2];
#pragma unroll
        for (int j = 0; j < 8; ++j) {
            qa[0][j] = (_Float16)((float)q0r[j] * 0.18033688f);
            qa[1][j] = (_Float16)((float)q1r[j] * 0.18033688f);
        }

        f32x4 o_[4];
#pragma unroll
        for (int ft = 0; ft < 4; ++ft) { o_[ft][0] = 0.f; o_[ft][1] = 0.f; o_[ft][2] = 0.f; o_[ft][3] = 0.f; }
        float lp[4] = {0.f, 0.f, 0.f, 0.f};

        for (int kt = 0; kt < ntiles; ++kt) {
            const int cur = kt & 1;
            // K(kt) landed (V(kt) still in flight), collective visibility
            WAITVM(2);
            __builtin_amdgcn_s_barrier();

            // prefetch tile kt+1 into buf[cur^1]: K issues then V issues
            if (kt + 1 < ntiles) {
                const int k0n = (kt + 1) * 64;
#pragma unroll
                for (int i = 0; i < 2; ++i) {
                    const int c = 2 * w + i;
                    ASYNC_COPY16(Kb + (size_t)(k0n + c * 8 + rsub) * HD + cswz,
                                 &Ks[cur ^ 1][c * 8][0]);
                }
#pragma unroll
                for (int i = 0; i < 2; ++i) {
                    const int c = 2 * w + i;
                    ASYNC_COPY16(Vtb + (size_t)(c * 8 + rsub) * SEQ + k0n + cswz,
                                 &Vs[cur ^ 1][c * 8][0]);
                }
            }

            // ---- S = Q K^T : 8 MFMAs (swizzled conflict-free reads) ----
            f32x4 s[4];
#pragma unroll
            for (int f = 0; f < 4; ++f) { s[f][0] = 0.f; s[f][1] = 0.f; s[f][2] = 0.f; s[f][3] = 0.f; }
#pragma unroll
            for (int c = 0; c < 2; ++c)
#pragma unroll
                for (int f = 0; f < 4; ++f) {
                    half8 kb = LDSFRAG(&Ks[cur][0][0], 16 * f + l15, 32 * c + 8 * lg);
                    s[f] = __builtin_amdgcn_mfma_f32_16x16x32_f16(qa[c], kb, s[f], 0, 0, 0);
                }

            // ---- p = exp2(s), mask, stash ----
            const bool dg = (kt == qt);
#pragma unroll
            for (int f = 0; f < 4; ++f)
#pragma unroll
                for (int r = 0; r < 4; ++r) {
                    float p = EXP2(s[f][r]);
                    if (dg && (16 * f + l15 > 16 * w + 4 * lg + r)) p = 0.f;
                    lp[r] += p;
                    Ps[w][4 * lg + r][16 * f + l15] = (_Float16)p;
                }

            // V(kt) landed (kt+1's 4 loads stay in flight), collective vis.
            if (kt + 1 < ntiles) { WAITVM(4); } else { WAITVM(0); }
            __builtin_amdgcn_s_barrier();

            // ---- O += P V : 8 MFMAs ----
            half8 pa[2];
            pa[0] = *(const half8*)&Ps[w][l15][8 * lg];
            pa[1] = *(const half8*)&Ps[w][l15][32 + 8 * lg];
#pragma unroll
            for (int c = 0; c < 2; ++c)
#pragma unroll
                for (int ft = 0; ft < 4; ++ft) {
                    half8 vb = LDSFRAG(&Vs[cur][0][0], 16 * ft + l15, 32 * c + 8 * lg);
                    o_[ft] = __builtin_amdgcn_mfma_f32_16x16x32_f16(pa[c], vb, o_[ft], 0, 0, 0);
                }
        }

        // ---- epilogue ----
#pragma unroll
        for (int r = 0; r < 4; ++r) {
            float rs = lp[r];
            rs += __shfl_xor(rs, 1);
            rs += __shfl_xor(rs, 2);
            rs += __shfl_xor(rs, 4);
            rs += __shfl_xor(rs, 8);
            const float inv = 1.0f / rs;
            _Float16* orow = O + (size_t)(b * SEQ + q0 + 16 * w + 4 * lg + r) * D_MODEL + h * HD + l15;
#pragma unroll
            for (int ft = 0; ft < 4; ++ft) orow[16 * ft] = (_Float16)(o_[ft][r] * inv);
        }
        __syncthreads();  // drains stores/LDS before pass-1 restage
    }
#undef WAITVM
}

// ---------------------------------------------------------------------------
extern "C" void kernel_launch(void* const* d_in, const int* in_sizes, int n_in,
                              void* d_out, int out_size, void* d_ws, size_t ws_size,
                              hipStream_t stream)
{
    const float* x  = (const float*)d_in[0];
    const float* wq = (const float*)d_in[1];
    const float* bq = (const float*)d_in[2];
    const float* wk = (const float*)d_in[3];
    const float* bk = (const float*)d_in[4];
    const float* wv = (const float*)d_in[5];
    const float* bv = (const float*)d_in[6];
    const float* wo = (const float*)d_in[7];
    const float* bo = (const float*)d_in[8];
    float* out = (float*)d_out;

    const size_t SZ = (size_t)MTOT * D_MODEL;  // 8388608
    const size_t WZ = (size_t)D_MODEL * D_MODEL;

    _Float16* xh  = (_Float16*)d_ws;
    _Float16* wtq = xh + SZ;
    _Float16* wtk = wtq + WZ;
    _Float16* wtv = wtk + WZ;
    _Float16* wto = wtv + WZ;
    _Float16* Qh  = wto + WZ;
    _Float16* Kh  = Qh + SZ;
    _Float16* Vtg = Kh + SZ;   // V, already transposed [bh][d][s]
    _Float16* AOh = Vtg + SZ;  // total ~88 MiB

    // fused prep: x cvt (blocks 0..255) + 4 weight transposes (256..1279)
    prep<<<dim3(1280), 256, 0, stream>>>(x, xh, wq, wk, wv, wo, wtq, wtk, wtv, wto);
    // QKV projection: XCD-affinity 1D grid (1536 blocks), glds staging
    gemm_mfma<1><<<dim3(1536), 256, 0, stream>>>(xh, wtq, wtk, wtv, bq, bk, bv, Qh, Kh, Vtg);
    // attention: 1D grid, bid = qt*64 + bh -> bh-XCD affinity
    attn_fwd_mfma<<<dim3(1024), 256, 0, stream>>>(Qh, Kh, Vtg, AOh);
    // output projection: XCD-affinity 1D grid (512 blocks)
    gemm_mfma<0><<<dim3(512), 256, 0, stream>>>(AOh, wto, wto, wto, bo, bo, bo, out, out, out);
}

// Round 7
// 274.389 us; speedup vs baseline: 1.0726x; 1.0099x over previous
//
#include <hip/hip_runtime.h>
#include <cstddef>

#define D_MODEL 1024
#define NH 16
#define HD 64
#define BATCH 4
#define SEQ 2048
#define MTOT (BATCH * SEQ)  // 8192

typedef _Float16 half8 __attribute__((ext_vector_type(8)));
typedef _Float16 half4v __attribute__((ext_vector_type(4)));
typedef float f32x4 __attribute__((ext_vector_type(4)));

#if __has_builtin(__builtin_amdgcn_exp2f)
#define EXP2(x) __builtin_amdgcn_exp2f(x)
#else
#define EXP2(x) __expf((x)*0.69314718056f)
#endif

// async global->LDS, 16B per lane. LDS dest must be wave-uniform base (+lane*16 implicit).
#define ASYNC_COPY16(g, l)                                                    \
    __builtin_amdgcn_global_load_lds(                                         \
        (__attribute__((address_space(1))) const void*)(g),                   \
        (__attribute__((address_space(3))) void*)(l), 16, 0, 0)

// Swizzled LDS access: logical element (R, CH f16-cols) of a [*][64] f16 tile
// lives at byte R*128 + ((CH*2) ^ ((R&7)<<4)).  Any producer (glds with
// inverse-swz global source, or ds_write at the same swizzled offset) pairs
// with this read: a wave's 64 lanes reading one column-slice across 16 rows
// land on distinct 16B slots -> conflict-free (proven 0-conflict in the GEMM).
#define LDSFRAG(S, R, CH)                                                     \
    (*(const half8*)((const char*)(S) + ((R) << 7) +                          \
                     ((((CH) << 1)) ^ (((R) & 7) << 4))))
// matching swizzled-write address (byte pointer) for row R, f16-col CH
#define LDSWADDR(S, R, CH)                                                    \
    ((half8*)((char*)(S) + ((R) << 7) + ((((CH) << 1)) ^ (((R) & 7) << 4))))

// ---------------------------------------------------------------------------
// Fused prep (unchanged):
//   blocks 0..255    : x fp32 -> f16 (4096 half8 chunks per block)
//   blocks 256..1279 : 4 weight matrices fp32 [k][n] -> f16 transposed [n][k]
// ---------------------------------------------------------------------------
__global__ __launch_bounds__(256) void prep(
    const float* __restrict__ x, _Float16* __restrict__ xh,
    const float* __restrict__ W0, const float* __restrict__ W1,
    const float* __restrict__ W2, const float* __restrict__ W3,
    _Float16* __restrict__ T0, _Float16* __restrict__ T1,
    _Float16* __restrict__ T2, _Float16* __restrict__ T3)
{
    __shared__ float T[64][65];
    const int bid = blockIdx.x;
    if (bid < 256) {
        const size_t base = (size_t)bid * 4096 + threadIdx.x;
#pragma unroll
        for (int it = 0; it < 16; ++it) {
            const size_t i = base + (size_t)it * 256;
            const float4* p = (const float4*)x + 2 * i;
            float4 a = p[0], b = p[1];
            half8 h;
            h[0] = (_Float16)a.x; h[1] = (_Float16)a.y; h[2] = (_Float16)a.z; h[3] = (_Float16)a.w;
            h[4] = (_Float16)b.x; h[5] = (_Float16)b.y; h[6] = (_Float16)b.z; h[7] = (_Float16)b.w;
            *((half8*)xh + i) = h;
        }
    } else {
        const int t = bid - 256;
        const int mtx = t >> 8;
        const float* W = (mtx == 0) ? W0 : (mtx == 1) ? W1 : (mtx == 2) ? W2 : W3;
        _Float16*   Wt = (mtx == 0) ? T0 : (mtx == 1) ? T1 : (mtx == 2) ? T2 : T3;
        const int tile = t & 255;
        const int k0 = (tile >> 4) * 64, n0 = (tile & 15) * 64;
        const int r = threadIdx.x >> 4, c4 = (threadIdx.x & 15) * 4;

#pragma unroll
        for (int i = 0; i < 4; ++i) {
            float4 v = *(const float4*)(W + (size_t)(k0 + r + 16 * i) * 1024 + n0 + c4);
            T[r + 16 * i][c4 + 0] = v.x; T[r + 16 * i][c4 + 1] = v.y;
            T[r + 16 * i][c4 + 2] = v.z; T[r + 16 * i][c4 + 3] = v.w;
        }
        __syncthreads();
#pragma unroll
        for (int i = 0; i < 4; ++i) {
            const int n = r + 16 * i;
            half4v h;
            h[0] = (_Float16)T[c4 + 0][n]; h[1] = (_Float16)T[c4 + 1][n];
            h[2] = (_Float16)T[c4 + 2][n]; h[3] = (_Float16)T[c4 + 3][n];
            *(half4v*)(Wt + (size_t)(n0 + n) * 1024 + k0 + c4) = h;
        }
    }
}

// ---------------------------------------------------------------------------
// MFMA f16 GEMM — EXACT round-1 version (proven 80.5 us QKV / 0 conflicts):
// m97-structure, global_load_lds staging, linear [128][64] LDS (BK=64),
// both-sides XOR swizzle, 2 barriers per K-step, 128^2 tile, 4 waves,
// 32 KB LDS -> ~3 blocks/CU. XCD-affinity 1D grid.
// QKV=1: c = L>>6: z = c/8 in {Q,K,V}, x-block = c%8.
//        z in {0,1}: f16 [bh][s][hd]; z==2: V transposed [bh][d][s].
// QKV=0: single output, f32 [m][n]. c = L>>6 = x-block.
// ---------------------------------------------------------------------------
template <int QKV>
__global__ __launch_bounds__(256) void gemm_mfma(
    const _Float16* __restrict__ A,
    const _Float16* __restrict__ Bt0, const _Float16* __restrict__ Bt1, const _Float16* __restrict__ Bt2,
    const float* __restrict__ bi0, const float* __restrict__ bi1, const float* __restrict__ bi2,
    void* __restrict__ C0, void* __restrict__ C1, void* __restrict__ C2)
{
    const int L = blockIdx.x;
    const int y = L & 63;
    const int c_ = L >> 6;
    const int z  = QKV ? (c_ >> 3) : 0;
    const int xb = QKV ? (c_ & 7) : c_;

    const _Float16* Bt = (z == 0) ? Bt0 : (z == 1) ? Bt1 : Bt2;
    const float*   bia = (z == 0) ? bi0 : (z == 1) ? bi1 : bi2;
    void*            C = (z == 0) ? C0  : (z == 1) ? C1  : C2;

    __shared__ _Float16 As[128][64];
    __shared__ _Float16 Bs[128][64];

    const int tid  = threadIdx.x;
    const int w    = tid >> 6;
    const int lane = tid & 63;
    const int l15  = lane & 15;
    const int lg   = lane >> 4;
    const int m0 = y * 128;
    const int n0 = xb * 128;
    const int wm = (w >> 1) * 64, wn = (w & 1) * 64;

    const int rsub = lane >> 3;                       // 0..7
    const int cswz = ((lane & 7) ^ rsub) * 8;         // halves

    const _Float16* gA = A  + (size_t)(m0 + 32 * w + rsub) * 1024 + cswz;
    const _Float16* gB = Bt + (size_t)(n0 + 32 * w + rsub) * 1024 + cswz;
    char* lA = (char*)As + (size_t)(w * 4) * 1024;
    char* lB = (char*)Bs + (size_t)(w * 4) * 1024;

    f32x4 acc[4][4];
#pragma unroll
    for (int i = 0; i < 4; ++i)
#pragma unroll
        for (int j = 0; j < 4; ++j) { acc[i][j][0] = 0.f; acc[i][j][1] = 0.f; acc[i][j][2] = 0.f; acc[i][j][3] = 0.f; }

    for (int kt = 0; kt < 16; ++kt) {
        const int k0 = kt * 64;
        __syncthreads();  // all reads of previous tile done before overwrite
#pragma unroll
        for (int i = 0; i < 4; ++i) {
            ASYNC_COPY16(gA + (size_t)(8 * i) * 1024 + k0, lA + i * 1024);
            ASYNC_COPY16(gB + (size_t)(8 * i) * 1024 + k0, lB + i * 1024);
        }
        __syncthreads();  // compiler drains vmcnt(0) before s_barrier -> tile visible

#pragma unroll
        for (int c = 0; c < 2; ++c) {
            half8 af[4], bf[4];
#pragma unroll
            for (int i = 0; i < 4; ++i) af[i] = LDSFRAG(As, wm + 16 * i + l15, 32 * c + 8 * lg);
#pragma unroll
            for (int j = 0; j < 4; ++j) bf[j] = LDSFRAG(Bs, wn + 16 * j + l15, 32 * c + 8 * lg);
#pragma unroll
            for (int i = 0; i < 4; ++i)
#pragma unroll
                for (int j = 0; j < 4; ++j)
                    acc[i][j] = __builtin_amdgcn_mfma_f32_16x16x32_f16(af[i], bf[j], acc[i][j], 0, 0, 0);
        }
    }

    float bvv[4];
#pragma unroll
    for (int j = 0; j < 4; ++j) bvv[j] = bia[n0 + wn + 16 * j + l15];

#pragma unroll
    for (int i = 0; i < 4; ++i)
#pragma unroll
        for (int j = 0; j < 4; ++j)
#pragma unroll
            for (int r = 0; r < 4; ++r) {
                const int m = m0 + wm + 16 * i + 4 * lg + r;
                const int n = n0 + wn + 16 * j + l15;
                const float val = acc[i][j][r] + bvv[j];
                if (QKV) {
                    const int bb = m >> 11, ss = m & 2047, hh = n >> 6, hd = n & 63;
                    if (z < 2)   // Q, K: [bh][s][hd]
                        ((_Float16*)C)[((size_t)(bb * NH + hh) * SEQ + ss) * HD + hd] = (_Float16)val;
                    else         // V: transposed [bh][d][s]
                        ((_Float16*)C)[((size_t)(bb * NH + hh) * HD + hd) * SEQ + ss] = (_Float16)val;
                } else {
                    ((float*)C)[(size_t)m * 1024 + n] = val;
                }
            }
}

// ---------------------------------------------------------------------------
// Causal flash attention v7 = round-0 structure (reg-prefetch + ds_write,
// single-buffered, 2 __syncthreads/tile — the 4-blocks/CU 75us baseline)
// + three bounded upgrades proven this session:
//  (1) bh->XCD affinity 1D grid (bid = qt*64+bh; 64%8==0 -> bid%8 = bh%8):
//      all 16 q-blocks of a bh on one XCD; FETCH 191->34 MB (round-6 PMC).
//  (2) Ks/Vs pitch-80 -> [64][64] + XOR swizzle: ds_write_b128 at swizzled
//      offset (bijective per row; min-cycle writes), LDSFRAG reads ->
//      conflict-free K/V reads (same formula as the 0-conflict GEMM).
//  (3) LDS 30.7 -> 26.6 KB -> __launch_bounds__(256,6): 6 blocks/CU (was 4)
//      for latency hiding (round-6 diagnosis: 45% no-issue cycles at 3/CU).
// Ps path deliberately untouched (one variable set per round).
// ---------------------------------------------------------------------------
__global__ __launch_bounds__(256, 6) void attn_fwd_mfma(
    const _Float16* __restrict__ Q, const _Float16* __restrict__ K,
    const _Float16* __restrict__ Vt, _Float16* __restrict__ O)
{
    __shared__ _Float16 Ks[64][64];
    __shared__ _Float16 Vs[64][64];
    __shared__ _Float16 Ps[4][16][80];

    const int tid  = threadIdx.x;
    const int w    = tid >> 6;
    const int lane = tid & 63;
    const int l15  = lane & 15;
    const int lg   = lane >> 4;

    const int bid = blockIdx.x;
    const int bh  = bid & 63;          // bid%8 == bh%8 -> XCD affinity
    const int qtb = bid >> 6;          // 0..15
    const int b  = bh >> 4, h = bh & 15;

    const _Float16* Qb  = Q  + (size_t)bh * SEQ * HD;
    const _Float16* Kb  = K  + (size_t)bh * SEQ * HD;   // [s][d]
    const _Float16* Vtb = Vt + (size_t)bh * HD * SEQ;   // [d][s]

    const int srow = tid >> 3;         // 0..31
    const int scol = (tid & 7) * 8;    // f16 cols

    for (int pass = 0; pass < 2; ++pass) {
        const int qt = pass ? qtb : (31 - qtb);
        const int q0 = qt * 64;
        const int ntiles = qt + 1;

        half8 qa[2];
        {
            const _Float16* qp = Qb + (size_t)(q0 + 16 * w + l15) * HD + 8 * lg;
            qa[0] = *(const half8*)(qp);
            qa[1] = *(const half8*)(qp + 32);
#pragma unroll
            for (int c = 0; c < 2; ++c)
#pragma unroll
                for (int j = 0; j < 8; ++j)
                    qa[c][j] = (_Float16)((float)qa[c][j] * 0.18033688f);
        }

        f32x4 o_[4];
#pragma unroll
        for (int ft = 0; ft < 4; ++ft) { o_[ft][0] = 0.f; o_[ft][1] = 0.f; o_[ft][2] = 0.f; o_[ft][3] = 0.f; }
        float lp[4] = {0.f, 0.f, 0.f, 0.f};

        half8 kreg[2], vreg[2];
#pragma unroll
        for (int j = 0; j < 2; ++j) {
            kreg[j] = *(const half8*)(Kb  + (size_t)(srow + 32 * j) * HD + scol);
            vreg[j] = *(const half8*)(Vtb + (size_t)(srow + 32 * j) * SEQ + scol);
        }

        for (int kt = 0; kt < ntiles; ++kt) {
            __syncthreads();
#pragma unroll
            for (int j = 0; j < 2; ++j) {
                const int row = srow + 32 * j;
                *LDSWADDR(Ks, row, scol) = kreg[j];
                *LDSWADDR(Vs, row, scol) = vreg[j];
            }
            __syncthreads();

            if (kt + 1 < ntiles) {
                const int k0 = (kt + 1) * 64;
#pragma unroll
                for (int j = 0; j < 2; ++j) {
                    kreg[j] = *(const half8*)(Kb  + (size_t)(k0 + srow + 32 * j) * HD + scol);
                    vreg[j] = *(const half8*)(Vtb + (size_t)(srow + 32 * j) * SEQ + k0 + scol);
                }
            }

            // ---- S = Q K^T : 8 MFMAs (conflict-free swizzled reads) ----
            f32x4 s[4];
#pragma unroll
            for (int f = 0; f < 4; ++f) { s[f][0] = 0.f; s[f][1] = 0.f; s[f][2] = 0.f; s[f][3] = 0.f; }
#pragma unroll
            for (int c = 0; c < 2; ++c)
#pragma unroll
                for (int f = 0; f < 4; ++f) {
                    half8 kb = LDSFRAG(Ks, 16 * f + l15, 32 * c + 8 * lg);
                    s[f] = __builtin_amdgcn_mfma_f32_16x16x32_f16(qa[c], kb, s[f], 0, 0, 0);
                }

            // ---- p = exp2(s), mask, stash ----
            const bool dg = (kt == qt);
#pragma unroll
            for (int f = 0; f < 4; ++f)
#pragma unroll
                for (int r = 0; r < 4; ++r) {
                    float p = EXP2(s[f][r]);
                    if (dg && (16 * f + l15 > 16 * w + 4 * lg + r)) p = 0.f;
                    lp[r] += p;
                    Ps[w][4 * lg + r][16 * f + l15] = (_Float16)p;
                }

            // ---- O += P V : 8 MFMAs ----
            half8 pa[2];
            pa[0] = *(const half8*)&Ps[w][l15][8 * lg];
            pa[1] = *(const half8*)&Ps[w][l15][32 + 8 * lg];
#pragma unroll
            for (int c = 0; c < 2; ++c)
#pragma unroll
                for (int ft = 0; ft < 4; ++ft) {
                    half8 vb = LDSFRAG(Vs, 16 * ft + l15, 32 * c + 8 * lg);
                    o_[ft] = __builtin_amdgcn_mfma_f32_16x16x32_f16(pa[c], vb, o_[ft], 0, 0, 0);
                }
        }

        // ---- epilogue ----
#pragma unroll
        for (int r = 0; r < 4; ++r) {
            float rs = lp[r];
            rs += __shfl_xor(rs, 1);
            rs += __shfl_xor(rs, 2);
            rs += __shfl_xor(rs, 4);
            rs += __shfl_xor(rs, 8);
            const float inv = 1.0f / rs;
            _Float16* orow = O + (size_t)(b * SEQ + q0 + 16 * w + 4 * lg + r) * D_MODEL + h * HD + l15;
#pragma unroll
            for (int ft = 0; ft < 4; ++ft) orow[16 * ft] = (_Float16)(o_[ft][r] * inv);
        }
        __syncthreads();  // Ps/Ks/Vs reuse across passes
    }
}

// ---------------------------------------------------------------------------
extern "C" void kernel_launch(void* const* d_in, const int* in_sizes, int n_in,
                              void* d_out, int out_size, void* d_ws, size_t ws_size,
                              hipStream_t stream)
{
    const float* x  = (const float*)d_in[0];
    const float* wq = (const float*)d_in[1];
    const float* bq = (const float*)d_in[2];
    const float* wk = (const float*)d_in[3];
    const float* bk = (const float*)d_in[4];
    const float* wv = (const float*)d_in[5];
    const float* bv = (const float*)d_in[6];
    const float* wo = (const float*)d_in[7];
    const float* bo = (const float*)d_in[8];
    float* out = (float*)d_out;

    const size_t SZ = (size_t)MTOT * D_MODEL;  // 8388608
    const size_t WZ = (size_t)D_MODEL * D_MODEL;

    _Float16* xh  = (_Float16*)d_ws;
    _Float16* wtq = xh + SZ;
    _Float16* wtk = wtq + WZ;
    _Float16* wtv = wtk + WZ;
    _Float16* wto = wtv + WZ;
    _Float16* Qh  = wto + WZ;
    _Float16* Kh  = Qh + SZ;
    _Float16* Vtg = Kh + SZ;   // V, already transposed [bh][d][s]
    _Float16* AOh = Vtg + SZ;  // total ~88 MiB

    // fused prep: x cvt (blocks 0..255) + 4 weight transposes (256..1279)
    prep<<<dim3(1280), 256, 0, stream>>>(x, xh, wq, wk, wv, wo, wtq, wtk, wtv, wto);
    // QKV projection: XCD-affinity 1D grid (1536 blocks), glds staging
    gemm_mfma<1><<<dim3(1536), 256, 0, stream>>>(xh, wtq, wtk, wtv, bq, bk, bv, Qh, Kh, Vtg);
    // attention: 1D grid, bid = qt*64 + bh -> bh-XCD affinity
    attn_fwd_mfma<<<dim3(1024), 256, 0, stream>>>(Qh, Kh, Vtg, AOh);
    // output projection: XCD-affinity 1D grid (512 blocks)
    gemm_mfma<0><<<dim3(512), 256, 0, stream>>>(AOh, wto, wto, wto, bo, bo, bo, out, out, out);
}

// Round 8
// 268.932 us; speedup vs baseline: 1.0944x; 1.0203x over previous
//
#include <hip/hip_runtime.h>
#include <cstddef>

#define D_MODEL 1024
#define NH 16
#define HD 64
#define BATCH 4
#define SEQ 2048
#define MTOT (BATCH * SEQ)  // 8192

typedef _Float16 half8 __attribute__((ext_vector_type(8)));
typedef _Float16 half4v __attribute__((ext_vector_type(4)));
typedef float f32x4 __attribute__((ext_vector_type(4)));

#if __has_builtin(__builtin_amdgcn_exp2f)
#define EXP2(x) __builtin_amdgcn_exp2f(x)
#else
#define EXP2(x) __expf((x)*0.69314718056f)
#endif

// async global->LDS, 16B per lane. LDS dest must be wave-uniform base (+lane*16 implicit).
#define ASYNC_COPY16(g, l)                                                    \
    __builtin_amdgcn_global_load_lds(                                         \
        (__attribute__((address_space(1))) const void*)(g),                   \
        (__attribute__((address_space(3))) void*)(l), 16, 0, 0)

// Swizzled LDS access: logical element (R, CH f16-cols) of a [*][64] f16 tile
// lives at byte R*128 + ((CH*2) ^ ((R&7)<<4)).  Any producer (glds with
// inverse-swz global source, or ds_write at the same swizzled offset) pairs
// with this read: a wave's 64 lanes reading one column-slice across 16 rows
// land on distinct 16B slots -> conflict-free (proven 0-conflict in the GEMM).
#define LDSFRAG(S, R, CH)                                                     \
    (*(const half8*)((const char*)(S) + ((R) << 7) +                          \
                     ((((CH) << 1)) ^ (((R) & 7) << 4))))
// matching swizzled-write address (byte pointer) for row R, f16-col CH
#define LDSWADDR(S, R, CH)                                                    \
    ((half8*)((char*)(S) + ((R) << 7) + ((((CH) << 1)) ^ (((R) & 7) << 4))))

// ---------------------------------------------------------------------------
// Fused prep (unchanged):
//   blocks 0..255    : x fp32 -> f16 (4096 half8 chunks per block)
//   blocks 256..1279 : 4 weight matrices fp32 [k][n] -> f16 transposed [n][k]
// ---------------------------------------------------------------------------
__global__ __launch_bounds__(256) void prep(
    const float* __restrict__ x, _Float16* __restrict__ xh,
    const float* __restrict__ W0, const float* __restrict__ W1,
    const float* __restrict__ W2, const float* __restrict__ W3,
    _Float16* __restrict__ T0, _Float16* __restrict__ T1,
    _Float16* __restrict__ T2, _Float16* __restrict__ T3)
{
    __shared__ float T[64][65];
    const int bid = blockIdx.x;
    if (bid < 256) {
        const size_t base = (size_t)bid * 4096 + threadIdx.x;
#pragma unroll
        for (int it = 0; it < 16; ++it) {
            const size_t i = base + (size_t)it * 256;
            const float4* p = (const float4*)x + 2 * i;
            float4 a = p[0], b = p[1];
            half8 h;
            h[0] = (_Float16)a.x; h[1] = (_Float16)a.y; h[2] = (_Float16)a.z; h[3] = (_Float16)a.w;
            h[4] = (_Float16)b.x; h[5] = (_Float16)b.y; h[6] = (_Float16)b.z; h[7] = (_Float16)b.w;
            *((half8*)xh + i) = h;
        }
    } else {
        const int t = bid - 256;
        const int mtx = t >> 8;
        const float* W = (mtx == 0) ? W0 : (mtx == 1) ? W1 : (mtx == 2) ? W2 : W3;
        _Float16*   Wt = (mtx == 0) ? T0 : (mtx == 1) ? T1 : (mtx == 2) ? T2 : T3;
        const int tile = t & 255;
        const int k0 = (tile >> 4) * 64, n0 = (tile & 15) * 64;
        const int r = threadIdx.x >> 4, c4 = (threadIdx.x & 15) * 4;

#pragma unroll
        for (int i = 0; i < 4; ++i) {
            float4 v = *(const float4*)(W + (size_t)(k0 + r + 16 * i) * 1024 + n0 + c4);
            T[r + 16 * i][c4 + 0] = v.x; T[r + 16 * i][c4 + 1] = v.y;
            T[r + 16 * i][c4 + 2] = v.z; T[r + 16 * i][c4 + 3] = v.w;
        }
        __syncthreads();
#pragma unroll
        for (int i = 0; i < 4; ++i) {
            const int n = r + 16 * i;
            half4v h;
            h[0] = (_Float16)T[c4 + 0][n]; h[1] = (_Float16)T[c4 + 1][n];
            h[2] = (_Float16)T[c4 + 2][n]; h[3] = (_Float16)T[c4 + 3][n];
            *(half4v*)(Wt + (size_t)(n0 + n) * 1024 + k0 + c4) = h;
        }
    }
}

// ---------------------------------------------------------------------------
// MFMA f16 GEMM — EXACT round-1 version (proven 80.5 us QKV / 0 conflicts):
// m97-structure, global_load_lds staging, linear [128][64] LDS (BK=64),
// both-sides XOR swizzle, 2 barriers per K-step, 128^2 tile, 4 waves,
// 32 KB LDS -> ~3 blocks/CU. XCD-affinity 1D grid.
// ---------------------------------------------------------------------------
template <int QKV>
__global__ __launch_bounds__(256) void gemm_mfma(
    const _Float16* __restrict__ A,
    const _Float16* __restrict__ Bt0, const _Float16* __restrict__ Bt1, const _Float16* __restrict__ Bt2,
    const float* __restrict__ bi0, const float* __restrict__ bi1, const float* __restrict__ bi2,
    void* __restrict__ C0, void* __restrict__ C1, void* __restrict__ C2)
{
    const int L = blockIdx.x;
    const int y = L & 63;
    const int c_ = L >> 6;
    const int z  = QKV ? (c_ >> 3) : 0;
    const int xb = QKV ? (c_ & 7) : c_;

    const _Float16* Bt = (z == 0) ? Bt0 : (z == 1) ? Bt1 : Bt2;
    const float*   bia = (z == 0) ? bi0 : (z == 1) ? bi1 : bi2;
    void*            C = (z == 0) ? C0  : (z == 1) ? C1  : C2;

    __shared__ _Float16 As[128][64];
    __shared__ _Float16 Bs[128][64];

    const int tid  = threadIdx.x;
    const int w    = tid >> 6;
    const int lane = tid & 63;
    const int l15  = lane & 15;
    const int lg   = lane >> 4;
    const int m0 = y * 128;
    const int n0 = xb * 128;
    const int wm = (w >> 1) * 64, wn = (w & 1) * 64;

    const int rsub = lane >> 3;                       // 0..7
    const int cswz = ((lane & 7) ^ rsub) * 8;         // halves

    const _Float16* gA = A  + (size_t)(m0 + 32 * w + rsub) * 1024 + cswz;
    const _Float16* gB = Bt + (size_t)(n0 + 32 * w + rsub) * 1024 + cswz;
    char* lA = (char*)As + (size_t)(w * 4) * 1024;
    char* lB = (char*)Bs + (size_t)(w * 4) * 1024;

    f32x4 acc[4][4];
#pragma unroll
    for (int i = 0; i < 4; ++i)
#pragma unroll
        for (int j = 0; j < 4; ++j) { acc[i][j][0] = 0.f; acc[i][j][1] = 0.f; acc[i][j][2] = 0.f; acc[i][j][3] = 0.f; }

    for (int kt = 0; kt < 16; ++kt) {
        const int k0 = kt * 64;
        __syncthreads();  // all reads of previous tile done before overwrite
#pragma unroll
        for (int i = 0; i < 4; ++i) {
            ASYNC_COPY16(gA + (size_t)(8 * i) * 1024 + k0, lA + i * 1024);
            ASYNC_COPY16(gB + (size_t)(8 * i) * 1024 + k0, lB + i * 1024);
        }
        __syncthreads();  // compiler drains vmcnt(0) before s_barrier -> tile visible

#pragma unroll
        for (int c = 0; c < 2; ++c) {
            half8 af[4], bf[4];
#pragma unroll
            for (int i = 0; i < 4; ++i) af[i] = LDSFRAG(As, wm + 16 * i + l15, 32 * c + 8 * lg);
#pragma unroll
            for (int j = 0; j < 4; ++j) bf[j] = LDSFRAG(Bs, wn + 16 * j + l15, 32 * c + 8 * lg);
#pragma unroll
            for (int i = 0; i < 4; ++i)
#pragma unroll
                for (int j = 0; j < 4; ++j)
                    acc[i][j] = __builtin_amdgcn_mfma_f32_16x16x32_f16(af[i], bf[j], acc[i][j], 0, 0, 0);
        }
    }

    float bvv[4];
#pragma unroll
    for (int j = 0; j < 4; ++j) bvv[j] = bia[n0 + wn + 16 * j + l15];

#pragma unroll
    for (int i = 0; i < 4; ++i)
#pragma unroll
        for (int j = 0; j < 4; ++j)
#pragma unroll
            for (int r = 0; r < 4; ++r) {
                const int m = m0 + wm + 16 * i + 4 * lg + r;
                const int n = n0 + wn + 16 * j + l15;
                const float val = acc[i][j][r] + bvv[j];
                if (QKV) {
                    const int bb = m >> 11, ss = m & 2047, hh = n >> 6, hd = n & 63;
                    if (z < 2)   // Q, K: [bh][s][hd]
                        ((_Float16*)C)[((size_t)(bb * NH + hh) * SEQ + ss) * HD + hd] = (_Float16)val;
                    else         // V: transposed [bh][d][s]
                        ((_Float16*)C)[((size_t)(bb * NH + hh) * HD + hd) * SEQ + ss] = (_Float16)val;
                } else {
                    ((float*)C)[(size_t)m * 1024 + n] = val;
                }
            }
}

// ---------------------------------------------------------------------------
// Causal flash attention v8 = v7 + swapped-QK^T P layout (LDS-pipe fix).
// Round-7 diagnosis: LDS pipe ~75-90% busy; SQ_LDS_BANK_CONFLICT constant
// 4.33M across rounds 5-7 = all in the Ps path (16 scalar f16 writes/thread/
// tile, 8-way conflicted: row stride 160B -> 4-row bank period 0 mod 32).
// Fix: s = mfma(kb, qa) (operand swap; A/B fragment layouts are symmetric so
// no reloads) -> lane holds P[k=16f+4lg+r][q=l15]: 4 contiguous k per f ->
// ONE half4 write per f (4 packed writes, 2-way/free at pitch-72) instead of
// 16 scalar.  pa reads unchanged (Ps[q][k] is exactly PV's A-fragment).
// Moved with the swap: diag mask k=16f+4lg+r > q=16w+l15; lp -> single
// accumulator (all of a thread's p share q=l15), reduced shfl_xor 16,32;
// epilogue row-sum fetched via __shfl(rs, 4*lg+r).  LDS ops/tile 38 -> 26.
// ---------------------------------------------------------------------------
__global__ __launch_bounds__(256, 6) void attn_fwd_mfma(
    const _Float16* __restrict__ Q, const _Float16* __restrict__ K,
    const _Float16* __restrict__ Vt, _Float16* __restrict__ O)
{
    __shared__ _Float16 Ks[64][64];
    __shared__ _Float16 Vs[64][64];
    __shared__ _Float16 Ps[4][16][72];   // pitch 72 f16 = 144 B (16B-aligned rows)

    const int tid  = threadIdx.x;
    const int w    = tid >> 6;
    const int lane = tid & 63;
    const int l15  = lane & 15;
    const int lg   = lane >> 4;

    const int bid = blockIdx.x;
    const int bh  = bid & 63;          // bid%8 == bh%8 -> XCD affinity
    const int qtb = bid >> 6;          // 0..15
    const int b  = bh >> 4, h = bh & 15;

    const _Float16* Qb  = Q  + (size_t)bh * SEQ * HD;
    const _Float16* Kb  = K  + (size_t)bh * SEQ * HD;   // [s][d]
    const _Float16* Vtb = Vt + (size_t)bh * HD * SEQ;   // [d][s]

    const int srow = tid >> 3;         // 0..31
    const int scol = (tid & 7) * 8;    // f16 cols

    for (int pass = 0; pass < 2; ++pass) {
        const int qt = pass ? qtb : (31 - qtb);
        const int q0 = qt * 64;
        const int ntiles = qt + 1;

        half8 qa[2];
        {
            const _Float16* qp = Qb + (size_t)(q0 + 16 * w + l15) * HD + 8 * lg;
            qa[0] = *(const half8*)(qp);
            qa[1] = *(const half8*)(qp + 32);
#pragma unroll
            for (int c = 0; c < 2; ++c)
#pragma unroll
                for (int j = 0; j < 8; ++j)
                    qa[c][j] = (_Float16)((float)qa[c][j] * 0.18033688f);
        }

        f32x4 o_[4];
#pragma unroll
        for (int ft = 0; ft < 4; ++ft) { o_[ft][0] = 0.f; o_[ft][1] = 0.f; o_[ft][2] = 0.f; o_[ft][3] = 0.f; }
        float lp_t = 0.f;   // partial row-sum for q = l15 (swapped layout)

        half8 kreg[2], vreg[2];
#pragma unroll
        for (int j = 0; j < 2; ++j) {
            kreg[j] = *(const half8*)(Kb  + (size_t)(srow + 32 * j) * HD + scol);
            vreg[j] = *(const half8*)(Vtb + (size_t)(srow + 32 * j) * SEQ + scol);
        }

        for (int kt = 0; kt < ntiles; ++kt) {
            __syncthreads();
#pragma unroll
            for (int j = 0; j < 2; ++j) {
                const int row = srow + 32 * j;
                *LDSWADDR(Ks, row, scol) = kreg[j];
                *LDSWADDR(Vs, row, scol) = vreg[j];
            }
            __syncthreads();

            if (kt + 1 < ntiles) {
                const int k0 = (kt + 1) * 64;
#pragma unroll
                for (int j = 0; j < 2; ++j) {
                    kreg[j] = *(const half8*)(Kb  + (size_t)(k0 + srow + 32 * j) * HD + scol);
                    vreg[j] = *(const half8*)(Vtb + (size_t)(srow + 32 * j) * SEQ + k0 + scol);
                }
            }

            // ---- S^T = K Q^T : 8 MFMAs, swapped operands ----
            // lane holds P[k = 16f + 4lg + r][q = l15]
            f32x4 s[4];
#pragma unroll
            for (int f = 0; f < 4; ++f) { s[f][0] = 0.f; s[f][1] = 0.f; s[f][2] = 0.f; s[f][3] = 0.f; }
#pragma unroll
            for (int c = 0; c < 2; ++c)
#pragma unroll
                for (int f = 0; f < 4; ++f) {
                    half8 kb = LDSFRAG(Ks, 16 * f + l15, 32 * c + 8 * lg);
                    s[f] = __builtin_amdgcn_mfma_f32_16x16x32_f16(kb, qa[c], s[f], 0, 0, 0);
                }

            // ---- p = exp2(s), mask, packed stash (half4 per f) ----
            const bool dg = (kt == qt);
#pragma unroll
            for (int f = 0; f < 4; ++f) {
                half4v ph;
#pragma unroll
                for (int r = 0; r < 4; ++r) {
                    float p = EXP2(s[f][r]);
                    if (dg && (16 * f + 4 * lg + r > 16 * w + l15)) p = 0.f;
                    lp_t += p;
                    ph[r] = (_Float16)p;
                }
                *(half4v*)&Ps[w][l15][16 * f + 4 * lg] = ph;
            }

            // ---- O += P V : 8 MFMAs (pa reads unchanged: Ps[q][k]) ----
            half8 pa[2];
            pa[0] = *(const half8*)&Ps[w][l15][8 * lg];
            pa[1] = *(const half8*)&Ps[w][l15][32 + 8 * lg];
#pragma unroll
            for (int c = 0; c < 2; ++c)
#pragma unroll
                for (int ft = 0; ft < 4; ++ft) {
                    half8 vb = LDSFRAG(Vs, 16 * ft + l15, 32 * c + 8 * lg);
                    o_[ft] = __builtin_amdgcn_mfma_f32_16x16x32_f16(pa[c], vb, o_[ft], 0, 0, 0);
                }
        }

        // ---- epilogue: row-sum lives at q=l15; O rows are q=4lg+r ----
        float rs = lp_t;
        rs += __shfl_xor(rs, 16);
        rs += __shfl_xor(rs, 32);
        // lanes 0..15 (any lg) now hold rowsum(q = l15)
#pragma unroll
        for (int r = 0; r < 4; ++r) {
            const float inv = 1.0f / __shfl(rs, 4 * lg + r, 64);
            _Float16* orow = O + (size_t)(b * SEQ + q0 + 16 * w + 4 * lg + r) * D_MODEL + h * HD + l15;
#pragma unroll
            for (int ft = 0; ft < 4; ++ft) orow[16 * ft] = (_Float16)(o_[ft][r] * inv);
        }
        __syncthreads();  // Ps/Ks/Vs reuse across passes
    }
}

// ---------------------------------------------------------------------------
extern "C" void kernel_launch(void* const* d_in, const int* in_sizes, int n_in,
                              void* d_out, int out_size, void* d_ws, size_t ws_size,
                              hipStream_t stream)
{
    const float* x  = (const float*)d_in[0];
    const float* wq = (const float*)d_in[1];
    const float* bq = (const float*)d_in[2];
    const float* wk = (const float*)d_in[3];
    const float* bk = (const float*)d_in[4];
    const float* wv = (const float*)d_in[5];
    const float* bv = (const float*)d_in[6];
    const float* wo = (const float*)d_in[7];
    const float* bo = (const float*)d_in[8];
    float* out = (float*)d_out;

    const size_t SZ = (size_t)MTOT * D_MODEL;  // 8388608
    const size_t WZ = (size_t)D_MODEL * D_MODEL;

    _Float16* xh  = (_Float16*)d_ws;
    _Float16* wtq = xh + SZ;
    _Float16* wtk = wtq + WZ;
    _Float16* wtv = wtk + WZ;
    _Float16* wto = wtv + WZ;
    _Float16* Qh  = wto + WZ;
    _Float16* Kh  = Qh + SZ;
    _Float16* Vtg = Kh + SZ;   // V, already transposed [bh][d][s]
    _Float16* AOh = Vtg + SZ;  // total ~88 MiB

    // fused prep: x cvt (blocks 0..255) + 4 weight transposes (256..1279)
    prep<<<dim3(1280), 256, 0, stream>>>(x, xh, wq, wk, wv, wo, wtq, wtk, wtv, wto);
    // QKV projection: XCD-affinity 1D grid (1536 blocks), glds staging
    gemm_mfma<1><<<dim3(1536), 256, 0, stream>>>(xh, wtq, wtk, wtv, bq, bk, bv, Qh, Kh, Vtg);
    // attention: 1D grid, bid = qt*64 + bh -> bh-XCD affinity
    attn_fwd_mfma<<<dim3(1024), 256, 0, stream>>>(Qh, Kh, Vtg, AOh);
    // output projection: XCD-affinity 1D grid (512 blocks)
    gemm_mfma<0><<<dim3(512), 256, 0, stream>>>(AOh, wto, wto, wto, bo, bo, bo, out, out, out);
}